// Round 12
// baseline (20.967 us; speedup 1.0000x reference)
//
#include <hip/hip_runtime.h>
#include <hip/hip_fp16.h>
#include <math.h>

// Problem constants: B=1024, IN_DIM=4096, OUT_DIM=4096, FAN_IN=8
#define BDIM 1024
#define IN_DIM 4096
#define OUT_DIM 4096
#define FAN_IN 8
#define NT 1024
#define TILE_B 4
#define OPT 4                 // outputs per thread (blocked: o = 4t..4t+3)

#define LOG2E 1.442695040888963f
#define LN2   0.6931471805599453f

typedef float f32x4 __attribute__((ext_vector_type(4)));

__device__ __forceinline__ float fast_exp(float v) {
    return exp2f(v * LOG2E);   // v_exp_f32
}

union H2U { __half2 h; unsigned int u; };

__global__ __launch_bounds__(NT, 4) void WeightedThresholdGate_53085795778563_kernel(
    const float* __restrict__ x,      // [B, IN_DIM]
    const int*   __restrict__ idx,    // [OUT_DIM, FAN_IN]
    const float* __restrict__ w,      // [OUT_DIM, FAN_IN]
    const float* __restrict__ theta,  // [OUT_DIM]
    const float* __restrict__ s_raw,  // [OUT_DIM]
    float*       __restrict__ out)    // [B, OUT_DIM]
{
    // Transposed f16 tile: xT[j] = {h(x[r0][j]),h(x[r1][j]) | h(x[r2][j]),h(x[r3][j])}
    // ds_read_b64 at j yields all 4 rows. 32 KiB.
    __shared__ __align__(16) uint2 xT[IN_DIM];

    const int t  = threadIdx.x;
    const int b0 = blockIdx.x * TILE_B;

    // ---- stage: 4 x global_load_dwordx4 per thread (1 KB/wave-instr) ----
    {
        const float4* __restrict__ xv0 = reinterpret_cast<const float4*>(x + (size_t)(b0 + 0) * IN_DIM);
        const float4* __restrict__ xv1 = reinterpret_cast<const float4*>(x + (size_t)(b0 + 1) * IN_DIM);
        const float4* __restrict__ xv2 = reinterpret_cast<const float4*>(x + (size_t)(b0 + 2) * IN_DIM);
        const float4* __restrict__ xv3 = reinterpret_cast<const float4*>(x + (size_t)(b0 + 3) * IN_DIM);
        const float4 r0 = xv0[t];
        const float4 r1 = xv1[t];
        const float4 r2 = xv2[t];
        const float4 r3 = xv3[t];
        const float e0[4] = {r0.x, r0.y, r0.z, r0.w};
        const float e1[4] = {r1.x, r1.y, r1.z, r1.w};
        const float e2[4] = {r2.x, r2.y, r2.z, r2.w};
        const float e3[4] = {r3.x, r3.y, r3.z, r3.w};
#pragma unroll
        for (int jj = 0; jj < 4; ++jj) {
            H2U lo, hi;
            lo.h = __floats2half2_rn(e0[jj], e1[jj]);   // rows 0,1
            hi.h = __floats2half2_rn(e2[jj], e3[jj]);   // rows 2,3
            xT[4 * t + jj] = make_uint2(lo.u, hi.u);
        }
    }
    __syncthreads();

    // ---- gather: blocked outputs o = 4t..4t+3 ----
    // theta/s_raw: one dwordx4 each covers all 4 outputs
    const float4 th4 = reinterpret_cast<const float4*>(theta)[t];
    const float4 sr4 = reinterpret_cast<const float4*>(s_raw)[t];
    const float  thv[4] = {th4.x, th4.y, th4.z, th4.w};
    const float  srv[4] = {sr4.x, sr4.y, sr4.z, sr4.w};

    float g[OPT][TILE_B];   // [output i][batch row] — fully unrolled, stays in VGPRs

#pragma unroll
    for (int i = 0; i < OPT; ++i) {
        const int o = 4 * t + i;

        const int4*   ip = reinterpret_cast<const int4*>(idx + (size_t)o * FAN_IN);
        const float4* wp = reinterpret_cast<const float4*>(w  + (size_t)o * FAN_IN);
        const int4   i0 = ip[0], i1 = ip[1];
        const float4 w0 = wp[0], w1 = wp[1];

        float a0 = 0.f, a1 = 0.f, a2 = 0.f, a3 = 0.f;

#define GATHER(J, WF)                                              \
        {                                                          \
            const uint2 gg = xT[(J)];                              \
            H2U glo, ghi; glo.u = gg.x; ghi.u = gg.y;              \
            const float2 f01 = __half22float2(glo.h);              \
            const float2 f23 = __half22float2(ghi.h);              \
            a0 = fmaf(f01.x, (WF), a0);                            \
            a1 = fmaf(f01.y, (WF), a1);                            \
            a2 = fmaf(f23.x, (WF), a2);                            \
            a3 = fmaf(f23.y, (WF), a3);                            \
        }

        GATHER(i0.x, w0.x); GATHER(i0.y, w0.y);
        GATHER(i0.z, w0.z); GATHER(i0.w, w0.w);
        GATHER(i1.x, w1.x); GATHER(i1.y, w1.y);
        GATHER(i1.z, w1.z); GATHER(i1.w, w1.w);
#undef GATHER

        const float sr = srv[i];
        const float sp = fmaxf(sr, 0.0f) + LN2 * log2f(1.0f + fast_exp(-fabsf(sr)));
        const float s  = sp + 1e-6f;
        const float th = thv[i];

        g[i][0] = 1.0f / (1.0f + fast_exp(-s * (a0 - th)));
        g[i][1] = 1.0f / (1.0f + fast_exp(-s * (a1 - th)));
        g[i][2] = 1.0f / (1.0f + fast_exp(-s * (a2 - th)));
        g[i][3] = 1.0f / (1.0f + fast_exp(-s * (a3 - th)));
    }

    // ---- out: 4 x nontemporal dwordx4, perfectly coalesced ----
#pragma unroll
    for (int r = 0; r < TILE_B; ++r) {
        f32x4 v;
        v.x = g[0][r]; v.y = g[1][r]; v.z = g[2][r]; v.w = g[3][r];
        f32x4* orow = reinterpret_cast<f32x4*>(out + (size_t)(b0 + r) * OUT_DIM);
        __builtin_nontemporal_store(v, &orow[t]);
    }
}

extern "C" void kernel_launch(void* const* d_in, const int* in_sizes, int n_in,
                              void* d_out, int out_size, void* d_ws, size_t ws_size,
                              hipStream_t stream) {
    const float* x     = (const float*)d_in[0];
    const int*   idx   = (const int*)  d_in[1];
    const float* w     = (const float*)d_in[2];
    const float* theta = (const float*)d_in[3];
    const float* s_raw = (const float*)d_in[4];
    float* out = (float*)d_out;

    dim3 grid(BDIM / TILE_B);   // 256 blocks, 1 per CU
    dim3 block(NT);             // 1024 threads = 16 waves = 4/SIMD
    WeightedThresholdGate_53085795778563_kernel<<<grid, block, 0, stream>>>(
        x, idx, w, theta, s_raw, out);
}

// Round 14
// 13.765 us; speedup vs baseline: 1.5231x; 1.5231x over previous
//
#include <hip/hip_runtime.h>
#include <hip/hip_fp16.h>
#include <math.h>

// Problem constants: B=1024, IN_DIM=4096, OUT_DIM=4096, FAN_IN=8
#define BDIM 1024
#define IN_DIM 4096
#define OUT_DIM 4096
#define FAN_IN 8
#define NT 1024
#define TILE_B 4
#define NTILES (BDIM / TILE_B)   // 256
#define HALF_OUT (OUT_DIM / 2)   // 2048
#define OPT (HALF_OUT / NT)      // 2 outputs per thread

#define LOG2E 1.442695040888963f
#define LN2   0.6931471805599453f

__device__ __forceinline__ float fast_exp(float v) {
    return exp2f(v * LOG2E);   // v_exp_f32
}

union H2U { __half2 h; unsigned int u; };

__global__ __launch_bounds__(NT, 8) void WeightedThresholdGate_53085795778563_kernel(
    const float* __restrict__ x,      // [B, IN_DIM]
    const int*   __restrict__ idx,    // [OUT_DIM, FAN_IN]
    const float* __restrict__ w,      // [OUT_DIM, FAN_IN]
    const float* __restrict__ theta,  // [OUT_DIM]
    const float* __restrict__ s_raw,  // [OUT_DIM]
    float*       __restrict__ out)    // [B, OUT_DIM]
{
    // Output-split tiles: blocks (T) and (T+256) both own batch rows 4T..4T+3
    // but each gathers HALF the outputs. bid%8 is equal for the pair -> same
    // XCD -> the partner's x-stage is an L2 hit (x footprint/XCD = 2MB < 4MB).
    // Each CU hosts 2 blocks (32KB LDS, <=64 VGPR): one block's stage
    // overlaps the other's gather.
    __shared__ __align__(8) uint2 xT[IN_DIM];   // 32 KiB, f16 transposed tile

    const int t    = threadIdx.x;
    const int tile = blockIdx.x & (NTILES - 1);
    const int half = blockIdx.x >> 8;
    const int b0   = tile * TILE_B;

    const float* __restrict__ xr0 = x + (size_t)(b0 + 0) * IN_DIM;
    const float* __restrict__ xr1 = x + (size_t)(b0 + 1) * IN_DIM;
    const float* __restrict__ xr2 = x + (size_t)(b0 + 2) * IN_DIM;
    const float* __restrict__ xr3 = x + (size_t)(b0 + 3) * IN_DIM;

    // Stage (identical to R10 = best measured): scalar coalesced loads,
    // cvt_pkrtz f16 pack, lane-contiguous ds_write_b64 (conflict-free).
#pragma unroll
    for (int k = 0; k < IN_DIM / NT; ++k) {
        const int j = t + k * NT;
        H2U lo, hi;
        lo.h = __floats2half2_rn(xr0[j], xr1[j]);   // rows 0,1
        hi.h = __floats2half2_rn(xr2[j], xr3[j]);   // rows 2,3
        xT[j] = make_uint2(lo.u, hi.u);
    }
    __syncthreads();

#pragma unroll
    for (int i = 0; i < OPT; ++i) {
        const int o = half * HALF_OUT + t + i * NT;   // strided: coalesced idx/w/out

        const int4*   ip = reinterpret_cast<const int4*>(idx + (size_t)o * FAN_IN);
        const float4* wp = reinterpret_cast<const float4*>(w  + (size_t)o * FAN_IN);
        const int4   i0 = ip[0], i1 = ip[1];
        const float4 w0 = wp[0], w1 = wp[1];

        float a0 = 0.f, a1 = 0.f, a2 = 0.f, a3 = 0.f;

#define GATHER(J, WF)                                              \
        {                                                          \
            const uint2 gg = xT[(J)];                              \
            H2U glo, ghi; glo.u = gg.x; ghi.u = gg.y;              \
            const float2 f01 = __half22float2(glo.h);              \
            const float2 f23 = __half22float2(ghi.h);              \
            a0 = fmaf(f01.x, (WF), a0);                            \
            a1 = fmaf(f01.y, (WF), a1);                            \
            a2 = fmaf(f23.x, (WF), a2);                            \
            a3 = fmaf(f23.y, (WF), a3);                            \
        }

        GATHER(i0.x, w0.x); GATHER(i0.y, w0.y);
        GATHER(i0.z, w0.z); GATHER(i0.w, w0.w);
        GATHER(i1.x, w1.x); GATHER(i1.y, w1.y);
        GATHER(i1.z, w1.z); GATHER(i1.w, w1.w);
#undef GATHER

        const float th = theta[o];
        const float sr = s_raw[o];
        // softplus(sr)+1e-6, stable; log via v_log_f32: log1p(u)=log2(1+u)*ln2
        const float sp = fmaxf(sr, 0.0f) + LN2 * log2f(1.0f + fast_exp(-fabsf(sr)));
        const float s  = sp + 1e-6f;

        const float g0 = 1.0f / (1.0f + fast_exp(-s * (a0 - th)));
        const float g1 = 1.0f / (1.0f + fast_exp(-s * (a1 - th)));
        const float g2 = 1.0f / (1.0f + fast_exp(-s * (a2 - th)));
        const float g3 = 1.0f / (1.0f + fast_exp(-s * (a3 - th)));

        // Streamed output: nontemporal, coalesced dwords
        __builtin_nontemporal_store(g0, &out[(size_t)(b0 + 0) * OUT_DIM + o]);
        __builtin_nontemporal_store(g1, &out[(size_t)(b0 + 1) * OUT_DIM + o]);
        __builtin_nontemporal_store(g2, &out[(size_t)(b0 + 2) * OUT_DIM + o]);
        __builtin_nontemporal_store(g3, &out[(size_t)(b0 + 3) * OUT_DIM + o]);
    }
}

extern "C" void kernel_launch(void* const* d_in, const int* in_sizes, int n_in,
                              void* d_out, int out_size, void* d_ws, size_t ws_size,
                              hipStream_t stream) {
    const float* x     = (const float*)d_in[0];
    const int*   idx   = (const int*)  d_in[1];
    const float* w     = (const float*)d_in[2];
    const float* theta = (const float*)d_in[3];
    const float* s_raw = (const float*)d_in[4];
    float* out = (float*)d_out;

    dim3 grid(2 * NTILES);   // 512 blocks: pair (T, T+256) shares XCD + batch tile
    dim3 block(NT);          // 1024 threads; 2 blocks/CU -> 32 waves/CU
    WeightedThresholdGate_53085795778563_kernel<<<grid, block, 0, stream>>>(
        x, idx, w, theta, s_raw, out);
}